// Round 17
// baseline (320.635 us; speedup 1.0000x reference)
//
#include <hip/hip_runtime.h>
#include <hip/hip_bf16.h>
#include <stdint.h>

#define S_LEN 2048
#define NHEADS 16
#define HDIM 128
#define H_TOT 2048
#define BATCH 2
#define M_TOK 4096   // B*S
#define KDIM 2048

typedef __attribute__((ext_vector_type(8))) short bf16x8;
typedef __attribute__((ext_vector_type(4))) float f32x4;
typedef __attribute__((ext_vector_type(16))) float f32x16;

__device__ inline ushort bf16rn(float f) {
  union { float f; uint32_t u; } x; x.f = f;
  uint32_t r = x.u + 0x7FFF + ((x.u >> 16) & 1);
  return (ushort)(r >> 16);
}

// ---------------- fused f32 -> bf16 conversion: x + 4 weights in ONE launch ----------------
__global__ __launch_bounds__(256) void cvt5_bf16_kernel(const float* __restrict__ x,
                                                        const float* __restrict__ w0,
                                                        const float* __restrict__ w1,
                                                        const float* __restrict__ w2,
                                                        const float* __restrict__ w3,
                                                        ushort* __restrict__ xo,
                                                        ushort* __restrict__ o0,
                                                        ushort* __restrict__ o1,
                                                        ushort* __restrict__ o2,
                                                        ushort* __restrict__ o3) {
  const int NX4 = M_TOK * KDIM / 4;   // 1<<21 quads (x)
  const int NW4 = KDIM * KDIM / 4;    // 1<<20 quads (each weight)
  int i = blockIdx.x * blockDim.x + threadIdx.x;
  int stride = gridDim.x * blockDim.x;
  for (; i < NX4 + 4 * NW4; i += stride) {
    const float* in;
    ushort* out;
    int off;
    if (i < NX4) {
      in = x; out = xo; off = i;
    } else {
      int j = i - NX4;
      int seg = j >> 20;
      off = j & (NW4 - 1);
      in = (seg == 0) ? w0 : (seg == 1) ? w1 : (seg == 2) ? w2 : w3;
      out = (seg == 0) ? o0 : (seg == 1) ? o1 : (seg == 2) ? o2 : o3;
    }
    float4 v = reinterpret_cast<const float4*>(in)[off];
    ushort4 o;
    o.x = bf16rn(v.x); o.y = bf16rn(v.y); o.z = bf16rn(v.z); o.w = bf16rn(v.w);
    reinterpret_cast<ushort4*>(out)[off] = o;
  }
}

// ---------------- pipelined NT GEMM (round-6/13 best: 127.5us QKV) ----------------
// BM=128 BN=256 BK=64, 512 thr, triple-buffer, counted vmcnt(6), raw s_barrier.
// MODE 0: fused QKV epilogue -> fragment-native Q/K/V layouts (seg = bn>>11)
// MODE 2: f32 [m][n] + bias[n]
template<int MODE, int NBX>
__global__ __launch_bounds__(512) void gemm2(const ushort* __restrict__ A,
                                             const ushort* __restrict__ Bw,
                                             void* __restrict__ C0,
                                             void* __restrict__ C1,
                                             void* __restrict__ C2,
                                             const float* __restrict__ bias,
                                             float scale) {
  __shared__ __attribute__((aligned(16))) char lds[3 * 49152];  // [buf][A:16KB | B:32KB]
  const int K = KDIM;
  const int NKT = K / 64;  // 32
  int tid = threadIdx.x;
  int wave = tid >> 6, lane = tid & 63;
  int lanelo = lane & 15, lanehi = lane >> 4;
  int wr = wave >> 2, wc = wave & 3;  // 2M x 4N waves, 64x64 output each

  int bid = blockIdx.x;
  const int CHX = NBX / 8;
  int ii = bid >> 3;
  int bx = (bid & 7) * CHX + (ii % CHX);
  int by = ii / CHX;
  int bm = by * 128, bn = bx * 256;

  const ushort* srcA[2];
  const ushort* srcB[4];
#pragma unroll
  for (int i = 0; i < 2; i++) {
    int c = i * 512 + tid, row = c >> 3, slot = c & 7;
    srcA[i] = A + (size_t)(bm + row) * K + ((slot ^ (row & 7)) * 8);
  }
#pragma unroll
  for (int i = 0; i < 4; i++) {
    int c = i * 512 + tid, row = c >> 3, slot = c & 7;
    srcB[i] = Bw + (size_t)(bn + row) * K + ((slot ^ (row & 7)) * 8);
  }

#define STAGE(tile, buf)                                                                    \
  {                                                                                         \
    char* dA = lds + (buf) * 49152 + (size_t)tid * 16;                                      \
    char* dB = lds + (buf) * 49152 + 16384 + (size_t)tid * 16;                              \
    _Pragma("unroll") for (int i_ = 0; i_ < 2; i_++)                                        \
      __builtin_amdgcn_global_load_lds(                                                     \
          (const __attribute__((address_space(1))) void*)(srcA[i_] + (tile) * 64),          \
          (__attribute__((address_space(3))) void*)(dA + i_ * 8192), 16, 0, 0);             \
    _Pragma("unroll") for (int i_ = 0; i_ < 4; i_++)                                        \
      __builtin_amdgcn_global_load_lds(                                                     \
          (const __attribute__((address_space(1))) void*)(srcB[i_] + (tile) * 64),          \
          (__attribute__((address_space(3))) void*)(dB + i_ * 8192), 16, 0, 0);             \
  }

  f32x4 acc[4][4];
#pragma unroll
  for (int i = 0; i < 4; i++)
#pragma unroll
    for (int j = 0; j < 4; j++) acc[i][j] = (f32x4){0.f, 0.f, 0.f, 0.f};

  STAGE(0, 0);
  STAGE(1, 1);
  asm volatile("s_waitcnt vmcnt(6)" ::: "memory");
  __builtin_amdgcn_s_barrier();
  __builtin_amdgcn_sched_barrier(0);

  for (int t = 0; t < NKT; t++) {
    STAGE((t + 2) & (NKT - 1), (t + 2) % 3);

    const ushort* bufc = (const ushort*)(lds + (t % 3) * 49152);

    bf16x8 bfr[4][2];
#pragma unroll
    for (int nf = 0; nf < 4; nf++)
#pragma unroll
      for (int kh = 0; kh < 2; kh++) {
        int row = wc * 64 + nf * 16 + lanelo;
        int slot = (kh * 4 + lanehi) ^ (row & 7);
        bfr[nf][kh] = *reinterpret_cast<const bf16x8*>(&bufc[8192 + row * 64 + slot * 8]);
      }

    __builtin_amdgcn_s_setprio(1);
#pragma unroll
    for (int mf = 0; mf < 4; mf++) {
      int row = wr * 64 + mf * 16 + lanelo;
      bf16x8 af[2];
#pragma unroll
      for (int kh = 0; kh < 2; kh++) {
        int slot = (kh * 4 + lanehi) ^ (row & 7);
        af[kh] = *reinterpret_cast<const bf16x8*>(&bufc[row * 64 + slot * 8]);
      }
#pragma unroll
      for (int nf = 0; nf < 4; nf++)
#pragma unroll
        for (int kh = 0; kh < 2; kh++)
          acc[mf][nf] = __builtin_amdgcn_mfma_f32_16x16x32_bf16(af[kh], bfr[nf][kh],
                                                                acc[mf][nf], 0, 0, 0);
    }
    __builtin_amdgcn_s_setprio(0);

    asm volatile("s_waitcnt vmcnt(6)" ::: "memory");
    __builtin_amdgcn_s_barrier();
    __builtin_amdgcn_sched_barrier(0);
  }

  // ---------------- epilogue ----------------
  if (MODE == 2) {
    float* Cf = (float*)C0;
#pragma unroll
    for (int nf = 0; nf < 4; nf++) {
      int n = bn + wc * 64 + nf * 16 + lanelo;
      float bv = bias[n];
#pragma unroll
      for (int mf = 0; mf < 4; mf++)
#pragma unroll
        for (int q = 0; q < 4; q++) {
          int m = bm + wr * 64 + mf * 16 + lanehi * 4 + q;
          Cf[(size_t)m * H_TOT + n] = acc[mf][nf][q] + bv;
        }
    }
  } else {
    int seg = bn >> 11;
    ushort* dst = (seg == 0) ? (ushort*)C0 : (seg == 1) ? (ushort*)C1 : (ushort*)C2;
    float sc = (seg == 0) ? scale : 1.0f;
#pragma unroll
    for (int nf = 0; nf < 4; nf++) {
      int n = (bn & 2047) + wc * 64 + nf * 16 + lanelo;
      int h = n >> 7, d = n & 127;
#pragma unroll
      for (int mf = 0; mf < 4; mf++)
#pragma unroll
        for (int q = 0; q < 4; q++) {
          int m = bm + wr * 64 + mf * 16 + lanehi * 4 + q;
          int b = m >> 11, s = m & 2047;
          int bh = b * NHEADS + h;
          size_t idx;
          if (seg < 2) {
            idx = (((size_t)(bh * 64 + (s >> 5)) * 8 + (d >> 4)) * 64 +
                   ((d >> 3) & 1) * 32 + (s & 31)) * 8 + (d & 7);
          } else {
            int r = s & 15;
            int e = (r & 3) | ((r >> 1) & 4);
            int hi = (r >> 2) & 1;
            idx = (((size_t)(bh * 64 + (s >> 5)) * 8 + ((s >> 4) & 1) * 4 + (d >> 5)) * 64 +
                   hi * 32 + (d & 31)) * 8 + e;
          }
          dst[idx] = bf16rn(acc[mf][nf][q] * sc);
        }
    }
  }
#undef STAGE
}

// ---------------- flash attention v11: KVBLK=64, in-body PV, no ping-pong ----------------
// 4 waves/block, 32 q-rows/wave, 512 blocks. Per body: stage 16KB K-tile (2 s-tiles,
// 4 DMA issues/wave), load 16 V chunks direct-from-global at body top (fragment-native,
// fully coalesced; ~800cy of QK+softmax hides their latency), QK^T as two independent
// 8-chains (S_a/S_b), softmax, PV in-body. Halves barrier/sync count vs v8 (32 bodies),
// deletes the deferred-PV register ping-pong.
__global__ __launch_bounds__(256) void attn_kernel(const ushort* __restrict__ Qf,
                                                   const ushort* __restrict__ Kf,
                                                   const ushort* __restrict__ Vf,
                                                   ushort* __restrict__ Ob) {
  __shared__ __attribute__((aligned(16))) ushort Kl[2][16 * 512];  // 32 KB (two 8KB s-tiles)
  __shared__ float lsinv[4][32];
  int lane = threadIdx.x & 63, wave = threadIdx.x >> 6;  // 4 waves
  int hi = lane >> 5;

  // XCD-bijective swizzle (512 % 8 == 0): each XCD gets 64 consecutive swz = 4 heads.
  int bid = blockIdx.x;
  int swz = (bid & 7) * 64 + (bid >> 3);
  int bh = swz >> 4, qt = swz & 15;
  int b = bh >> 4, h = bh & 15;
  int qrow0 = qt * 128 + wave * 32;

  const bf16x8* Qv = reinterpret_cast<const bf16x8*>(Qf) +
                     ((size_t)(bh * 64 + qt * 4 + wave) * 8) * 64 + lane;
  bf16x8 qf[8];
#pragma unroll
  for (int kc = 0; kc < 8; kc++) qf[kc] = Qv[kc * 64];

  f32x16 oacc[4];
#pragma unroll
  for (int d32 = 0; d32 < 4; d32++)
#pragma unroll
    for (int r = 0; r < 16; r++) oacc[d32][r] = 0.f;
  float lsum = 0.f;
  int laneoff = lane * 8;
  const bf16x8* Vv = reinterpret_cast<const bf16x8*>(Vf) + ((size_t)bh * 64 * 8) * 64 + lane;

  // body kt2 covers s-tiles 2*kt2, 2*kt2+1 -> 16 contiguous K chunks; 4 DMA issues/wave
#define STAGE(kt2, bufsel)                                                                 \
  {                                                                                        \
    size_t gchunk = ((size_t)(bh * 64 + 2 * (kt2))) * 8;                                   \
    _Pragma("unroll")                                                                      \
    for (int i_ = 0; i_ < 4; i_++) {                                                       \
      int cc = wave * 4 + i_;                                                              \
      __builtin_amdgcn_global_load_lds(                                                    \
          (const __attribute__((address_space(1))) void*)(Kf + (gchunk + cc) * 512 +       \
                                                          laneoff),                        \
          (__attribute__((address_space(3))) void*)(&Kl[bufsel][cc * 512]), 16, 0, 0);     \
    }                                                                                      \
  }

  union pu { bf16x8 v; uint32_t u[4]; };

  STAGE(0, 0);
  asm volatile("s_waitcnt vmcnt(0)" ::: "memory");
  __syncthreads();

  const int NT2 = S_LEN / 64;  // 32 bodies

  for (int t = 0; t < NT2; t++) {
    if (t + 1 < NT2) STAGE(t + 1, (t + 1) & 1);

    // V(t): 16 coalesced chunk loads; consumed ~800cy later by PV
    bf16x8 vr[16];
#pragma unroll
    for (int i = 0; i < 16; i++) vr[i] = Vv[((size_t)(2 * t) * 8 + i) * 64];

    const ushort* lb = &Kl[t & 1][0];
    f32x16 Sa, Sb;
#pragma unroll
    for (int r = 0; r < 16; r++) { Sa[r] = 0.f; Sb[r] = 0.f; }
    __builtin_amdgcn_s_setprio(1);
#pragma unroll
    for (int kc = 0; kc < 8; kc++) {
      bf16x8 ka = *reinterpret_cast<const bf16x8*>(&lb[kc * 512 + laneoff]);
      bf16x8 kb = *reinterpret_cast<const bf16x8*>(&lb[(8 + kc) * 512 + laneoff]);
      Sa = __builtin_amdgcn_mfma_f32_32x32x16_bf16(ka, qf[kc], Sa, 0, 0, 0);
      Sb = __builtin_amdgcn_mfma_f32_32x32x16_bf16(kb, qf[kc], Sb, 0, 0, 0);
    }
    __builtin_amdgcn_s_setprio(0);

    // softmax numerators + pack (scale pre-folded into Q; no max-subtract)
    pu pa0, pa1, pb0, pb1;
#pragma unroll
    for (int j = 0; j < 4; j++) {
      float a0 = exp2f(Sa[2 * j]), a1 = exp2f(Sa[2 * j + 1]);
      float a2 = exp2f(Sa[8 + 2 * j]), a3 = exp2f(Sa[9 + 2 * j]);
      lsum += (a0 + a1) + (a2 + a3);
      uint32_t w0_, w1_;
      asm("v_cvt_pk_bf16_f32 %0, %1, %2" : "=v"(w0_) : "v"(a0), "v"(a1));
      asm("v_cvt_pk_bf16_f32 %0, %1, %2" : "=v"(w1_) : "v"(a2), "v"(a3));
      pa0.u[j] = w0_; pa1.u[j] = w1_;
      float b0 = exp2f(Sb[2 * j]), b1 = exp2f(Sb[2 * j + 1]);
      float b2 = exp2f(Sb[8 + 2 * j]), b3 = exp2f(Sb[9 + 2 * j]);
      lsum += (b0 + b1) + (b2 + b3);
      uint32_t w2_, w3_;
      asm("v_cvt_pk_bf16_f32 %0, %1, %2" : "=v"(w2_) : "v"(b0), "v"(b1));
      asm("v_cvt_pk_bf16_f32 %0, %1, %2" : "=v"(w3_) : "v"(b2), "v"(b3));
      pb0.u[j] = w2_; pb1.u[j] = w3_;
    }

    // PV in-body: both s-tiles into oacc
    __builtin_amdgcn_s_setprio(1);
#pragma unroll
    for (int d32 = 0; d32 < 4; d32++) {
      oacc[d32] = __builtin_amdgcn_mfma_f32_32x32x16_bf16(pa0.v, vr[d32], oacc[d32], 0, 0, 0);
      oacc[d32] = __builtin_amdgcn_mfma_f32_32x32x16_bf16(pa1.v, vr[4 + d32], oacc[d32], 0, 0, 0);
      oacc[d32] = __builtin_amdgcn_mfma_f32_32x32x16_bf16(pb0.v, vr[8 + d32], oacc[d32], 0, 0, 0);
      oacc[d32] = __builtin_amdgcn_mfma_f32_32x32x16_bf16(pb1.v, vr[12 + d32], oacc[d32], 0, 0, 0);
    }
    __builtin_amdgcn_s_setprio(0);

    asm volatile("s_waitcnt vmcnt(0)" ::: "memory");
    __syncthreads();
  }

  // ---- denominator: q-row lane&31 total = own + partner(lane^32) ----
  float total = lsum + __shfl_xor(lsum, 32);
  if (lane < 32) lsinv[wave][lane] = 1.0f / total;
  __syncthreads();

  // ---- store: D-layout row pattern -> token-major bf16 [b][s][h*128+d] ----
  float ls[16];
#pragma unroll
  for (int r = 0; r < 16; r++) ls[r] = lsinv[wave][(r & 3) + 8 * (r >> 2) + 4 * hi];
#pragma unroll
  for (int d32 = 0; d32 < 4; d32++)
#pragma unroll
    for (int r = 0; r < 16; r++) {
      int row = (r & 3) + 8 * (r >> 2) + 4 * hi;
      size_t idx = ((size_t)(b * S_LEN + qrow0 + row)) * H_TOT + h * HDIM + d32 * 32 + (lane & 31);
      Ob[idx] = bf16rn(oacc[d32][r] * ls[r]);
    }
#undef STAGE
}

// ---------------- host-side launch ----------------
extern "C" void kernel_launch(void* const* d_in, const int* in_sizes, int n_in,
                              void* d_out, int out_size, void* d_ws, size_t ws_size,
                              hipStream_t stream) {
  const float* x  = (const float*)d_in[0];
  const float* Wq = (const float*)d_in[1];
  const float* Wk = (const float*)d_in[2];
  const float* Wv = (const float*)d_in[3];
  const float* Wo = (const float*)d_in[4];
  const float* bo = (const float*)d_in[5];
  float* out = (float*)d_out;

  char* w = (char*)d_ws;
  ushort* xb  = (ushort*)w; w += (size_t)M_TOK * KDIM * 2;
  ushort* Wqb = (ushort*)w; w += (size_t)KDIM * KDIM * 2;   // Wqb,Wkb,Wvb contiguous: fused B
  ushort* Wkb = (ushort*)w; w += (size_t)KDIM * KDIM * 2;
  ushort* Wvb = (ushort*)w; w += (size_t)KDIM * KDIM * 2;
  ushort* Wob = (ushort*)w; w += (size_t)KDIM * KDIM * 2;
  ushort* Qh  = (ushort*)w; w += (size_t)M_TOK * KDIM * 2;
  ushort* Kh  = (ushort*)w; w += (size_t)M_TOK * KDIM * 2;
  ushort* Vt  = (ushort*)w; w += (size_t)M_TOK * KDIM * 2;
  ushort* Ob  = (ushort*)w; w += (size_t)M_TOK * KDIM * 2;

  // one fused conversion launch: x + Wq + Wk + Wv + Wo
  hipLaunchKernelGGL(cvt5_bf16_kernel, dim3(2048), dim3(256), 0, stream,
                     x, Wq, Wk, Wv, Wo, xb, Wqb, Wkb, Wvb, Wob);

  const float sl = 0.08838834764831845f * 1.4426950408889634f;  // HD^-0.5 * log2(e)

  // fused QKV: M=4096, N=6144 -> 32 x 24 tiles = 768 blocks
  hipLaunchKernelGGL((gemm2<0, 24>), dim3(768), dim3(512), 0, stream,
                     xb, Wqb, (void*)Qh, (void*)Kh, (void*)Vt, (const float*)nullptr, sl);

  hipLaunchKernelGGL(attn_kernel, dim3(512), dim3(256), 0, stream, Qh, Kh, Vt, Ob);

  // output projection: M=4096, N=2048 -> 32 x 8 tiles = 256 blocks
  hipLaunchKernelGGL((gemm2<2, 8>), dim3(256), dim3(512), 0, stream,
                     Ob, Wob, (void*)out, nullptr, nullptr, bo, 1.0f);
}

// Round 18
// 266.134 us; speedup vs baseline: 1.2048x; 1.2048x over previous
//
#include <hip/hip_runtime.h>
#include <hip/hip_bf16.h>
#include <stdint.h>

#define S_LEN 2048
#define NHEADS 16
#define HDIM 128
#define H_TOT 2048
#define BATCH 2
#define M_TOK 4096   // B*S
#define KDIM 2048

typedef __attribute__((ext_vector_type(8))) short bf16x8;
typedef __attribute__((ext_vector_type(4))) float f32x4;
typedef __attribute__((ext_vector_type(16))) float f32x16;

__device__ inline ushort bf16rn(float f) {
  union { float f; uint32_t u; } x; x.f = f;
  uint32_t r = x.u + 0x7FFF + ((x.u >> 16) & 1);
  return (ushort)(r >> 16);
}

// ---------------- fused f32 -> bf16 conversion: x + 4 weights in ONE launch ----------------
__global__ __launch_bounds__(256) void cvt5_bf16_kernel(const float* __restrict__ x,
                                                        const float* __restrict__ w0,
                                                        const float* __restrict__ w1,
                                                        const float* __restrict__ w2,
                                                        const float* __restrict__ w3,
                                                        ushort* __restrict__ xo,
                                                        ushort* __restrict__ o0,
                                                        ushort* __restrict__ o1,
                                                        ushort* __restrict__ o2,
                                                        ushort* __restrict__ o3) {
  const int NX4 = M_TOK * KDIM / 4;   // 1<<21 quads (x)
  const int NW4 = KDIM * KDIM / 4;    // 1<<20 quads (each weight)
  int i = blockIdx.x * blockDim.x + threadIdx.x;
  int stride = gridDim.x * blockDim.x;
  for (; i < NX4 + 4 * NW4; i += stride) {
    const float* in;
    ushort* out;
    int off;
    if (i < NX4) {
      in = x; out = xo; off = i;
    } else {
      int j = i - NX4;
      int seg = j >> 20;
      off = j & (NW4 - 1);
      in = (seg == 0) ? w0 : (seg == 1) ? w1 : (seg == 2) ? w2 : w3;
      out = (seg == 0) ? o0 : (seg == 1) ? o1 : (seg == 2) ? o2 : o3;
    }
    float4 v = reinterpret_cast<const float4*>(in)[off];
    ushort4 o;
    o.x = bf16rn(v.x); o.y = bf16rn(v.y); o.z = bf16rn(v.z); o.w = bf16rn(v.w);
    reinterpret_cast<ushort4*>(out)[off] = o;
  }
}

// ---------------- pipelined NT GEMM (measured best: 127us QKV) ----------------
// BM=128 BN=256 BK=64, 512 thr, triple-buffer, counted vmcnt(6), raw s_barrier.
// MODE 0: fused QKV epilogue -> fragment-native Q/K/V layouts (seg = bn>>11)
// MODE 2: f32 [m][n] + bias[n]
template<int MODE, int NBX>
__global__ __launch_bounds__(512) void gemm2(const ushort* __restrict__ A,
                                             const ushort* __restrict__ Bw,
                                             void* __restrict__ C0,
                                             void* __restrict__ C1,
                                             void* __restrict__ C2,
                                             const float* __restrict__ bias,
                                             float scale) {
  __shared__ __attribute__((aligned(16))) char lds[3 * 49152];  // [buf][A:16KB | B:32KB]
  const int K = KDIM;
  const int NKT = K / 64;  // 32
  int tid = threadIdx.x;
  int wave = tid >> 6, lane = tid & 63;
  int lanelo = lane & 15, lanehi = lane >> 4;
  int wr = wave >> 2, wc = wave & 3;  // 2M x 4N waves, 64x64 output each

  int bid = blockIdx.x;
  const int CHX = NBX / 8;
  int ii = bid >> 3;
  int bx = (bid & 7) * CHX + (ii % CHX);
  int by = ii / CHX;
  int bm = by * 128, bn = bx * 256;

  const ushort* srcA[2];
  const ushort* srcB[4];
#pragma unroll
  for (int i = 0; i < 2; i++) {
    int c = i * 512 + tid, row = c >> 3, slot = c & 7;
    srcA[i] = A + (size_t)(bm + row) * K + ((slot ^ (row & 7)) * 8);
  }
#pragma unroll
  for (int i = 0; i < 4; i++) {
    int c = i * 512 + tid, row = c >> 3, slot = c & 7;
    srcB[i] = Bw + (size_t)(bn + row) * K + ((slot ^ (row & 7)) * 8);
  }

#define STAGE(tile, buf)                                                                    \
  {                                                                                         \
    char* dA = lds + (buf) * 49152 + (size_t)tid * 16;                                      \
    char* dB = lds + (buf) * 49152 + 16384 + (size_t)tid * 16;                              \
    _Pragma("unroll") for (int i_ = 0; i_ < 2; i_++)                                        \
      __builtin_amdgcn_global_load_lds(                                                     \
          (const __attribute__((address_space(1))) void*)(srcA[i_] + (tile) * 64),          \
          (__attribute__((address_space(3))) void*)(dA + i_ * 8192), 16, 0, 0);             \
    _Pragma("unroll") for (int i_ = 0; i_ < 4; i_++)                                        \
      __builtin_amdgcn_global_load_lds(                                                     \
          (const __attribute__((address_space(1))) void*)(srcB[i_] + (tile) * 64),          \
          (__attribute__((address_space(3))) void*)(dB + i_ * 8192), 16, 0, 0);             \
  }

  f32x4 acc[4][4];
#pragma unroll
  for (int i = 0; i < 4; i++)
#pragma unroll
    for (int j = 0; j < 4; j++) acc[i][j] = (f32x4){0.f, 0.f, 0.f, 0.f};

  STAGE(0, 0);
  STAGE(1, 1);
  asm volatile("s_waitcnt vmcnt(6)" ::: "memory");
  __builtin_amdgcn_s_barrier();
  __builtin_amdgcn_sched_barrier(0);

  for (int t = 0; t < NKT; t++) {
    STAGE((t + 2) & (NKT - 1), (t + 2) % 3);

    const ushort* bufc = (const ushort*)(lds + (t % 3) * 49152);

    bf16x8 bfr[4][2];
#pragma unroll
    for (int nf = 0; nf < 4; nf++)
#pragma unroll
      for (int kh = 0; kh < 2; kh++) {
        int row = wc * 64 + nf * 16 + lanelo;
        int slot = (kh * 4 + lanehi) ^ (row & 7);
        bfr[nf][kh] = *reinterpret_cast<const bf16x8*>(&bufc[8192 + row * 64 + slot * 8]);
      }

    __builtin_amdgcn_s_setprio(1);
#pragma unroll
    for (int mf = 0; mf < 4; mf++) {
      int row = wr * 64 + mf * 16 + lanelo;
      bf16x8 af[2];
#pragma unroll
      for (int kh = 0; kh < 2; kh++) {
        int slot = (kh * 4 + lanehi) ^ (row & 7);
        af[kh] = *reinterpret_cast<const bf16x8*>(&bufc[row * 64 + slot * 8]);
      }
#pragma unroll
      for (int nf = 0; nf < 4; nf++)
#pragma unroll
        for (int kh = 0; kh < 2; kh++)
          acc[mf][nf] = __builtin_amdgcn_mfma_f32_16x16x32_bf16(af[kh], bfr[nf][kh],
                                                                acc[mf][nf], 0, 0, 0);
    }
    __builtin_amdgcn_s_setprio(0);

    asm volatile("s_waitcnt vmcnt(6)" ::: "memory");
    __builtin_amdgcn_s_barrier();
    __builtin_amdgcn_sched_barrier(0);
  }

  // ---------------- epilogue ----------------
  if (MODE == 2) {
    float* Cf = (float*)C0;
#pragma unroll
    for (int nf = 0; nf < 4; nf++) {
      int n = bn + wc * 64 + nf * 16 + lanelo;
      float bv = bias[n];
#pragma unroll
      for (int mf = 0; mf < 4; mf++)
#pragma unroll
        for (int q = 0; q < 4; q++) {
          int m = bm + wr * 64 + mf * 16 + lanehi * 4 + q;
          Cf[(size_t)m * H_TOT + n] = acc[mf][nf][q] + bv;
        }
    }
  } else {
    int seg = bn >> 11;
    ushort* dst = (seg == 0) ? (ushort*)C0 : (seg == 1) ? (ushort*)C1 : (ushort*)C2;
    float sc = (seg == 0) ? scale : 1.0f;
#pragma unroll
    for (int nf = 0; nf < 4; nf++) {
      int n = (bn & 2047) + wc * 64 + nf * 16 + lanelo;
      int h = n >> 7, d = n & 127;
#pragma unroll
      for (int mf = 0; mf < 4; mf++)
#pragma unroll
        for (int q = 0; q < 4; q++) {
          int m = bm + wr * 64 + mf * 16 + lanehi * 4 + q;
          int b = m >> 11, s = m & 2047;
          int bh = b * NHEADS + h;
          size_t idx;
          if (seg < 2) {
            idx = (((size_t)(bh * 64 + (s >> 5)) * 8 + (d >> 4)) * 64 +
                   ((d >> 3) & 1) * 32 + (s & 31)) * 8 + (d & 7);
          } else {
            int r = s & 15;
            int e = (r & 3) | ((r >> 1) & 4);
            int hi = (r >> 2) & 1;
            idx = (((size_t)(bh * 64 + (s >> 5)) * 8 + ((s >> 4) & 1) * 4 + (d >> 5)) * 64 +
                   hi * 32 + (d & 31)) * 8 + e;
          }
          dst[idx] = bf16rn(acc[mf][nf][q] * sc);
        }
    }
  }
#undef STAGE
}

// ---------------- flash attention v10 (measured best): K via LDS, V direct-from-global ----------------
// 4 waves/block, 32 q-rows/wave, 512 blocks. K staged in LDS (shared by 4 waves,
// 2 DMA issues/wave); V read from its fragment-native global layout (fully coalesced
// 1KB loads) into the NEXT body's register set — deferred-PV ping-pong gives each V
// load a full body (~1100cy) of slack, and the end-of-body drain happens after all
// compute (latency hidden). Load-ordering invariant: PV only ever consumes registers
// loaded one body earlier (v11's in-body PV violated this and serialized on staging).
__global__ __launch_bounds__(256) void attn_kernel(const ushort* __restrict__ Qf,
                                                   const ushort* __restrict__ Kf,
                                                   const ushort* __restrict__ Vf,
                                                   ushort* __restrict__ Ob) {
  __shared__ __attribute__((aligned(16))) ushort Kl[2][4096];  // K tile double buffer
  __shared__ float lsinv[4][32];
  int lane = threadIdx.x & 63, wave = threadIdx.x >> 6;  // 4 waves
  int hi = lane >> 5;

  // XCD-bijective swizzle (512 % 8 == 0): each XCD gets 64 consecutive swz = 4 heads.
  int bid = blockIdx.x;
  int swz = (bid & 7) * 64 + (bid >> 3);
  int bh = swz >> 4, qt = swz & 15;
  int b = bh >> 4, h = bh & 15;
  int qrow0 = qt * 128 + wave * 32;

  const bf16x8* Qv = reinterpret_cast<const bf16x8*>(Qf) +
                     ((size_t)(bh * 64 + qt * 4 + wave) * 8) * 64 + lane;
  bf16x8 qf[8];
#pragma unroll
  for (int kc = 0; kc < 8; kc++) qf[kc] = Qv[kc * 64];

  f32x16 oacc[4];
#pragma unroll
  for (int d32 = 0; d32 < 4; d32++)
#pragma unroll
    for (int r = 0; r < 16; r++) oacc[d32][r] = 0.f;
  float lsum = 0.f;
  int laneoff = lane * 8;
  // V fragment-native base for this head, lane folded in: chunk (kt*8 + i) at [chunk*64]
  const bf16x8* Vv = reinterpret_cast<const bf16x8*>(Vf) + ((size_t)bh * 64 * 8) * 64 + lane;

  // wave w stages K chunks 2w, 2w+1 (2 issues/wave)
#define STAGE(kt, bufsel)                                                                  \
  {                                                                                        \
    size_t gchunk = ((size_t)(bh * 64 + (kt))) * 8;                                        \
    _Pragma("unroll")                                                                      \
    for (int i_ = 0; i_ < 2; i_++) {                                                       \
      int cc = wave * 2 + i_;                                                              \
      __builtin_amdgcn_global_load_lds(                                                    \
          (const __attribute__((address_space(1))) void*)(Kf + (gchunk + cc) * 512 +       \
                                                          laneoff),                        \
          (__attribute__((address_space(3))) void*)(&Kl[bufsel][cc * 512]), 16, 0, 0);     \
    }                                                                                      \
  }

  union pu { bf16x8 v; uint32_t u[4]; };
  pu paA0, paA1, paB0, paB1;
  bf16x8 vrA[8], vrB[8];
  const bf16x8 bz = {0, 0, 0, 0, 0, 0, 0, 0};
#pragma unroll
  for (int j = 0; j < 4; j++) { paA0.u[j] = 0; paA1.u[j] = 0; }
#pragma unroll
  for (int i = 0; i < 8; i++) vrA[i] = bz;   // first PV is a 0*0 no-op

  STAGE(0, 0);
  asm volatile("s_waitcnt vmcnt(0)" ::: "memory");
  __syncthreads();

  const int NT = S_LEN / 32;  // 64 (even)

#define BODY(T, PI0, PI1, VI, PO0, PO1, VO)                                                 \
  {                                                                                         \
    if ((T) + 1 < NT) STAGE((T) + 1, ((T) + 1) & 1);                                        \
    _Pragma("unroll") for (int i_ = 0; i_ < 8; i_++)                                        \
      VO[i_] = Vv[((size_t)(T) * 8 + i_) * 64];   /* V(T): coalesced, lands by body end */  \
    const ushort* lb = &Kl[(T) & 1][0];                                                     \
    f32x16 S;                                                                               \
    _Pragma("unroll") for (int r = 0; r < 16; r++) S[r] = 0.f;                              \
    __builtin_amdgcn_s_setprio(1);                                                          \
    _Pragma("unroll") for (int kc = 0; kc < 8; kc++) {                                      \
      bf16x8 kfr = *reinterpret_cast<const bf16x8*>(&lb[kc * 512 + laneoff]);               \
      S = __builtin_amdgcn_mfma_f32_32x32x16_bf16(kfr, qf[kc], S, 0, 0, 0);                 \
    }                                                                                       \
    _Pragma("unroll") for (int d32 = 0; d32 < 4; d32++) {                                   \
      oacc[d32] = __builtin_amdgcn_mfma_f32_32x32x16_bf16(PI0.v, VI[d32], oacc[d32], 0, 0, 0); \
      oacc[d32] = __builtin_amdgcn_mfma_f32_32x32x16_bf16(PI1.v, VI[4 + d32], oacc[d32], 0, 0, 0); \
    }                                                                                       \
    __builtin_amdgcn_s_setprio(0);                                                          \
    float p_[16];                                                                           \
    _Pragma("unroll") for (int r = 0; r < 16; r++) { p_[r] = exp2f(S[r]); lsum += p_[r]; }  \
    _Pragma("unroll") for (int j = 0; j < 4; j++) {                                         \
      uint32_t w0_, w1_;                                                                    \
      asm("v_cvt_pk_bf16_f32 %0, %1, %2" : "=v"(w0_) : "v"(p_[2 * j]), "v"(p_[2 * j + 1])); \
      asm("v_cvt_pk_bf16_f32 %0, %1, %2" : "=v"(w1_) : "v"(p_[8 + 2 * j]), "v"(p_[9 + 2 * j])); \
      PO0.u[j] = w0_; PO1.u[j] = w1_;                                                       \
    }                                                                                       \
    asm volatile("s_waitcnt vmcnt(0)" ::: "memory");                                        \
    __syncthreads();                                                                        \
  }

  for (int t = 0; t < NT; t += 2) {
    BODY(t,     paA0, paA1, vrA, paB0, paB1, vrB);
    BODY(t + 1, paB0, paB1, vrB, paA0, paA1, vrA);
  }
  // final PV: A-side holds P(NT-1), V(NT-1)
#pragma unroll
  for (int d32 = 0; d32 < 4; d32++) {
    oacc[d32] = __builtin_amdgcn_mfma_f32_32x32x16_bf16(paA0.v, vrA[d32], oacc[d32], 0, 0, 0);
    oacc[d32] = __builtin_amdgcn_mfma_f32_32x32x16_bf16(paA1.v, vrA[4 + d32], oacc[d32], 0, 0, 0);
  }

  // ---- denominator: q-row lane&31 total = own + partner(lane^32) ----
  float total = lsum + __shfl_xor(lsum, 32);
  if (lane < 32) lsinv[wave][lane] = 1.0f / total;
  __syncthreads();

  // ---- store: D-layout row pattern -> token-major bf16 [b][s][h*128+d] ----
  float ls[16];
#pragma unroll
  for (int r = 0; r < 16; r++) ls[r] = lsinv[wave][(r & 3) + 8 * (r >> 2) + 4 * hi];
#pragma unroll
  for (int d32 = 0; d32 < 4; d32++)
#pragma unroll
    for (int r = 0; r < 16; r++) {
      int row = (r & 3) + 8 * (r >> 2) + 4 * hi;
      size_t idx = ((size_t)(b * S_LEN + qrow0 + row)) * H_TOT + h * HDIM + d32 * 32 + (lane & 31);
      Ob[idx] = bf16rn(oacc[d32][r] * ls[r]);
    }
#undef BODY
#undef STAGE
}

// ---------------- host-side launch ----------------
extern "C" void kernel_launch(void* const* d_in, const int* in_sizes, int n_in,
                              void* d_out, int out_size, void* d_ws, size_t ws_size,
                              hipStream_t stream) {
  const float* x  = (const float*)d_in[0];
  const float* Wq = (const float*)d_in[1];
  const float* Wk = (const float*)d_in[2];
  const float* Wv = (const float*)d_in[3];
  const float* Wo = (const float*)d_in[4];
  const float* bo = (const float*)d_in[5];
  float* out = (float*)d_out;

  char* w = (char*)d_ws;
  ushort* xb  = (ushort*)w; w += (size_t)M_TOK * KDIM * 2;
  ushort* Wqb = (ushort*)w; w += (size_t)KDIM * KDIM * 2;   // Wqb,Wkb,Wvb contiguous: fused B
  ushort* Wkb = (ushort*)w; w += (size_t)KDIM * KDIM * 2;
  ushort* Wvb = (ushort*)w; w += (size_t)KDIM * KDIM * 2;
  ushort* Wob = (ushort*)w; w += (size_t)KDIM * KDIM * 2;
  ushort* Qh  = (ushort*)w; w += (size_t)M_TOK * KDIM * 2;
  ushort* Kh  = (ushort*)w; w += (size_t)M_TOK * KDIM * 2;
  ushort* Vt  = (ushort*)w; w += (size_t)M_TOK * KDIM * 2;
  ushort* Ob  = (ushort*)w; w += (size_t)M_TOK * KDIM * 2;

  // one fused conversion launch: x + Wq + Wk + Wv + Wo
  hipLaunchKernelGGL(cvt5_bf16_kernel, dim3(2048), dim3(256), 0, stream,
                     x, Wq, Wk, Wv, Wo, xb, Wqb, Wkb, Wvb, Wob);

  const float sl = 0.08838834764831845f * 1.4426950408889634f;  // HD^-0.5 * log2(e)

  // fused QKV: M=4096, N=6144 -> 32 x 24 tiles = 768 blocks
  hipLaunchKernelGGL((gemm2<0, 24>), dim3(768), dim3(512), 0, stream,
                     xb, Wqb, (void*)Qh, (void*)Kh, (void*)Vt, (const float*)nullptr, sl);

  hipLaunchKernelGGL(attn_kernel, dim3(512), dim3(256), 0, stream, Qh, Kh, Vt, Ob);

  // output projection: M=4096, N=2048 -> 32 x 8 tiles = 256 blocks
  hipLaunchKernelGGL((gemm2<2, 8>), dim3(256), dim3(512), 0, stream,
                     Ob, Wob, (void*)out, nullptr, nullptr, bo, 1.0f);
}